// Round 13
// baseline (340.708 us; speedup 1.0000x reference)
//
#include <hip/hip_runtime.h>

// GraphSAGE 3-layer, N=50000, E=800000, D=128, D_OUT=64.
// R13: non-temporal streaming. Scatter: 4 dst ranges + nt loads of row/col/ew
// (streams no longer evict partially-assembled ep lines). Gathers: nt loads of
// the linear ep stream (preserves src slice L2 residency). Rest = R12.

#define D 128
#define K2 256
#define NQ 4            // col quarters
#define QW 12500        // quarter width (N/4)

typedef __attribute__((ext_vector_type(8))) short short8;
typedef __attribute__((ext_vector_type(4))) float floatx4;

__device__ inline unsigned short rne_bf16(float f) {
    unsigned int u = __float_as_uint(f);
    u += 0x7fffu + ((u >> 16) & 1u);
    return (unsigned short)(u >> 16);
}

__device__ inline int quarter_of(int c) {
    return (c >= 2 * QW) ? ((c >= 3 * QW) ? 3 : 2) : ((c >= QW) ? 1 : 0);
}

// ---------- prep: cast_x + cast_w(hi/lo) + hist4 in one launch ----------
__global__ void prep_kernel(const float* __restrict__ x, unsigned short* __restrict__ x_hi,
                            const float* __restrict__ W0, const float* __restrict__ W1,
                            const float* __restrict__ W2,
                            unsigned short* __restrict__ h0, unsigned short* __restrict__ l0,
                            unsigned short* __restrict__ h1, unsigned short* __restrict__ l1,
                            unsigned short* __restrict__ h2, unsigned short* __restrict__ l2,
                            const int* __restrict__ row, const int* __restrict__ col,
                            int* __restrict__ cnt, int n4, int E) {
    int b = blockIdx.x;
    int tid = threadIdx.x;
    if (b < 6250) {
        int i = b * 256 + tid;
        if (i < n4) {
            float4 v = reinterpret_cast<const float4*>(x)[i];
            ushort4 o;
            o.x = rne_bf16(v.x); o.y = rne_bf16(v.y); o.z = rne_bf16(v.z); o.w = rne_bf16(v.w);
            reinterpret_cast<ushort4*>(x_hi)[i] = o;
        }
    } else if (b < 6570) {
        int i = (b - 6250) * 256 + tid;
        const float* w; unsigned short *hi, *lo; int sidx, didx;
        if (i < 32768)      { w = W0; hi = h0; lo = l0; sidx = i; didx = i; }
        else if (i < 65536) { w = W1; hi = h1; lo = l1; sidx = i - 32768; didx = sidx; }
        else if (i < 81920) {
            w = W2; hi = h2; lo = l2;
            int i2 = i - 65536;            // Wcat 128x128
            int r = i2 >> 7, k = i2 & 127;
            sidx = (r < 64) ? (r * 256 + k) : ((r - 64) * 256 + 128 + k);
            didx = i2;
        }
        else return;
        float f = w[sidx];
        unsigned short h = rne_bf16(f);
        float fh = __uint_as_float(((unsigned int)h) << 16);
        hi[didx] = h;
        lo[didx] = rne_bf16(f - fh);
    } else {
        int e = (b - 6570) * 256 + tid;
        if (e < E) {
            int rw = __builtin_nontemporal_load(row + e);
            int c  = __builtin_nontemporal_load(col + e);
            atomicAdd(&cnt[rw * NQ + quarter_of(c)], 1);
        }
    }
}

// ---------- scans over 4N bins ----------
__global__ void scan1_kernel(const int* __restrict__ cnt, int* __restrict__ rowptr,
                             int* __restrict__ bsum, int NB) {
    __shared__ int s[256];
    int tid = threadIdx.x;
    int gid = blockIdx.x * 256 + tid;
    int v = (gid < NB) ? cnt[gid] : 0;
    s[tid] = v;
    __syncthreads();
    for (int off = 1; off < 256; off <<= 1) {
        int t = (tid >= off) ? s[tid - off] : 0;
        __syncthreads();
        s[tid] += t;
        __syncthreads();
    }
    if (gid < NB) rowptr[gid] = s[tid] - v;
    if (tid == 255) bsum[blockIdx.x] = s[255];
}

__global__ void scan2_kernel(int* __restrict__ bsum, int* __restrict__ boff, int nb) {
    __shared__ int s[1024];
    int tid = threadIdx.x;
    int v = (tid < nb) ? bsum[tid] : 0;
    s[tid] = v;
    __syncthreads();
    for (int off = 1; off < 1024; off <<= 1) {
        int t = (tid >= off) ? s[tid - off] : 0;
        __syncthreads();
        s[tid] += t;
        __syncthreads();
    }
    if (tid < nb) boff[tid] = s[tid] - v;
}

__global__ void scan3_kernel(int* __restrict__ rowptr, const int* __restrict__ boff,
                             int* __restrict__ cursor, int NB, int E) {
    int gid = blockIdx.x * 256 + threadIdx.x;
    if (gid < NB) {
        int v = rowptr[gid] + boff[gid >> 8];
        rowptr[gid] = v;
        cursor[gid] = v;
    } else if (gid == NB) {
        rowptr[NB] = E;
    }
}

// ---------- scatter: 4 dst ranges, nt streaming reads ----------
__global__ void scatter_ranged(const int* __restrict__ row, const int* __restrict__ col,
                               const float* __restrict__ ew, int* __restrict__ cursor,
                               int2* __restrict__ ep, int E) {
    int b = blockIdx.x;
    int r = b & 3;
    int q = b >> 2;
    int nchunk = gridDim.x >> 2;
    int chunk = (E + nchunk - 1) / nchunk;
    int e0 = q * chunk;
    int e1 = e0 + chunk; if (e1 > E) e1 = E;
    int lo = r * 12500, hi = lo + 12500;
    for (int e = e0 + (int)threadIdx.x; e < e1; e += (int)blockDim.x) {
        int rw = __builtin_nontemporal_load(row + e);
        if (rw >= lo && rw < hi) {
            int c = __builtin_nontemporal_load(col + e);
            float w = __builtin_nontemporal_load(ew + e);
            int key = rw * NQ + quarter_of(c);
            int p = atomicAdd(&cursor[key], 1);
            ep[p] = make_int2(c, __float_as_int(w));
        }
    }
}

// ---------- gather aggregation (bf16 src/dst), unroll x8, nt ep stream ----------
__device__ inline void accum8(float* acc, uint4 a, float w) {
    acc[0] += __uint_as_float(a.x << 16) * w;
    acc[1] += __uint_as_float(a.x & 0xffff0000u) * w;
    acc[2] += __uint_as_float(a.y << 16) * w;
    acc[3] += __uint_as_float(a.y & 0xffff0000u) * w;
    acc[4] += __uint_as_float(a.z << 16) * w;
    acc[5] += __uint_as_float(a.z & 0xffff0000u) * w;
    acc[6] += __uint_as_float(a.w << 16) * w;
    acc[7] += __uint_as_float(a.w & 0xffff0000u) * w;
}

__device__ inline void unpack_ep(long long v, int& c, float& w) {
    c = (int)(v & 0xffffffffLL);
    w = __int_as_float((int)(v >> 32));
}

__global__ void gather_agg_bf(const unsigned short* __restrict__ src, const int* __restrict__ rowptr4,
                              const long long* __restrict__ epL, unsigned short* __restrict__ agg, int N) {
    long long t = (long long)blockIdx.x * blockDim.x + threadIdx.x;
    int wid = (int)(t >> 6);
    int lane = threadIdx.x & 63;
    int slot = lane >> 4;
    int fl = lane & 15;
    int n = wid * 4 + slot;
    if (n >= N) return;
    int beg = rowptr4[n * 4], end = rowptr4[n * 4 + 4];
    float acc[8];
#pragma unroll
    for (int j = 0; j < 8; j++) acc[j] = 0.f;
    float ds = 0.f;
    int e = beg;
    for (; e + 7 < end; e += 8) {
        long long p[8];
#pragma unroll
        for (int u = 0; u < 8; u++) p[u] = __builtin_nontemporal_load(epL + e + u);
        uint4 a[8];
#pragma unroll
        for (int u = 0; u < 8; u++) {
            int c; float w; unpack_ep(p[u], c, w);
            a[u] = *reinterpret_cast<const uint4*>(src + (size_t)c * D + fl * 8);
        }
#pragma unroll
        for (int u = 0; u < 8; u++) {
            int c; float w; unpack_ep(p[u], c, w);
            accum8(acc, a[u], w);
            ds += w;
        }
    }
    for (; e + 3 < end; e += 4) {
        long long p[4];
#pragma unroll
        for (int u = 0; u < 4; u++) p[u] = __builtin_nontemporal_load(epL + e + u);
#pragma unroll
        for (int u = 0; u < 4; u++) {
            int c; float w; unpack_ep(p[u], c, w);
            uint4 a = *reinterpret_cast<const uint4*>(src + (size_t)c * D + fl * 8);
            accum8(acc, a, w);
            ds += w;
        }
    }
    for (; e < end; ++e) {
        long long p = __builtin_nontemporal_load(epL + e);
        int c; float w; unpack_ep(p, c, w);
        uint4 a = *reinterpret_cast<const uint4*>(src + (size_t)c * D + fl * 8);
        accum8(acc, a, w);
        ds += w;
    }
    float inv = 1.0f / (ds > 1.f ? ds : 1.f);
    uint4 o;
    o.x = (unsigned int)rne_bf16(acc[0] * inv) | ((unsigned int)rne_bf16(acc[1] * inv) << 16);
    o.y = (unsigned int)rne_bf16(acc[2] * inv) | ((unsigned int)rne_bf16(acc[3] * inv) << 16);
    o.z = (unsigned int)rne_bf16(acc[4] * inv) | ((unsigned int)rne_bf16(acc[5] * inv) << 16);
    o.w = (unsigned int)rne_bf16(acc[6] * inv) | ((unsigned int)rne_bf16(acc[7] * inv) << 16);
    *reinterpret_cast<uint4*>(agg + (size_t)n * D + fl * 8) = o;
}

// ---------- MFMA GEMM, whole-K W slice in LDS, one barrier (layers 0/1) ----------
template<bool RELU, bool BF16OUT, int OSTRIDE>
__global__ __launch_bounds__(256) void sage_gemm(
    const unsigned short* __restrict__ src, const unsigned short* __restrict__ agg,
    const unsigned short* __restrict__ Whi, const unsigned short* __restrict__ Wlo,
    const float* __restrict__ bias, float* __restrict__ outf,
    unsigned short* __restrict__ outb, int N) {
    __shared__ short sW[2][32][260];
    int tid = threadIdx.x;
    int c0 = blockIdx.y * 32;

    for (int i = tid; i < 2048; i += 256) {
        int h = i >> 10;
        int rem = i & 1023;
        int r = rem & 31;
        int k8 = rem >> 5;
        const unsigned short* wp = (h ? Wlo : Whi) + (size_t)(c0 + r) * K2 + k8 * 8;
        *reinterpret_cast<uint4*>(&sW[h][r][k8 * 8]) = *reinterpret_cast<const uint4*>(wp);
    }
    __syncthreads();

    int lane = tid & 63;
    int wv = tid >> 6;
    int nlane = lane & 15;
    int quad = lane >> 4;
    int m0 = blockIdx.x * 128 + wv * 32;
    int r0 = m0 + nlane;      if (r0 >= N) r0 = N - 1;   // clamped; stores guarded
    int r1 = m0 + 16 + nlane; if (r1 >= N) r1 = N - 1;

    short8 a[2][8];
#pragma unroll
    for (int ks = 0; ks < 8; ks++) {
        int k0 = ks * 32;
        const unsigned short* p0 = (k0 < D) ? (src + (size_t)r0 * D + k0)
                                            : (agg + (size_t)r0 * D + (k0 - D));
        const unsigned short* p1 = (k0 < D) ? (src + (size_t)r1 * D + k0)
                                            : (agg + (size_t)r1 * D + (k0 - D));
        a[0][ks] = *reinterpret_cast<const short8*>(p0 + quad * 8);
        a[1][ks] = *reinterpret_cast<const short8*>(p1 + quad * 8);
    }

    floatx4 acc[2][2];
#pragma unroll
    for (int mt = 0; mt < 2; mt++)
#pragma unroll
        for (int nt = 0; nt < 2; nt++) acc[mt][nt] = (floatx4){0.f, 0.f, 0.f, 0.f};

#pragma unroll
    for (int ks = 0; ks < 8; ks++) {
        int k0 = ks * 32;
#pragma unroll
        for (int nt = 0; nt < 2; nt++) {
            short8 bh = *reinterpret_cast<const short8*>(&sW[0][nt * 16 + nlane][k0 + quad * 8]);
            short8 bl = *reinterpret_cast<const short8*>(&sW[1][nt * 16 + nlane][k0 + quad * 8]);
            acc[0][nt] = __builtin_amdgcn_mfma_f32_16x16x32_bf16(a[0][ks], bh, acc[0][nt], 0, 0, 0);
            acc[0][nt] = __builtin_amdgcn_mfma_f32_16x16x32_bf16(a[0][ks], bl, acc[0][nt], 0, 0, 0);
            acc[1][nt] = __builtin_amdgcn_mfma_f32_16x16x32_bf16(a[1][ks], bh, acc[1][nt], 0, 0, 0);
            acc[1][nt] = __builtin_amdgcn_mfma_f32_16x16x32_bf16(a[1][ks], bl, acc[1][nt], 0, 0, 0);
        }
    }

#pragma unroll
    for (int nt = 0; nt < 2; nt++) {
        int c = c0 + nt * 16 + nlane;
        float bb = bias[c];
#pragma unroll
        for (int mt = 0; mt < 2; mt++) {
#pragma unroll
            for (int r = 0; r < 4; r++) {
                int node = m0 + mt * 16 + quad * 4 + r;
                if (node < N) {
                    float y = acc[mt][nt][r] + bb;
                    if (RELU) y = y > 0.f ? y : 0.f;
                    if (BF16OUT) outb[(size_t)node * OSTRIDE + c] = rne_bf16(y);
                    else         outf[(size_t)node * OSTRIDE + c] = y;
                }
            }
        }
    }
}

// ---------- layer-2 GEMM (K=128): ytop2 fp32, z2 bf16 ----------
__global__ __launch_bounds__(256) void sage_gemm2(
    const unsigned short* __restrict__ h1, const unsigned short* __restrict__ Whi,
    const unsigned short* __restrict__ Wlo, const float* __restrict__ b2,
    float* __restrict__ ytop2, unsigned short* __restrict__ z2, int N) {
    __shared__ short sW[2][32][132];
    int tid = threadIdx.x;
    int c0 = blockIdx.y * 32;

    for (int i = tid; i < 1024; i += 256) {
        int h = i >> 9;
        int rem = i & 511;
        int r = rem & 31;
        int k8 = rem >> 5;
        const unsigned short* wp = (h ? Wlo : Whi) + (size_t)(c0 + r) * 128 + k8 * 8;
        *reinterpret_cast<uint4*>(&sW[h][r][k8 * 8]) = *reinterpret_cast<const uint4*>(wp);
    }
    __syncthreads();

    int lane = tid & 63;
    int wv = tid >> 6;
    int nlane = lane & 15;
    int quad = lane >> 4;
    int m0 = blockIdx.x * 128 + wv * 32;
    int r0 = m0 + nlane;      if (r0 >= N) r0 = N - 1;
    int r1 = m0 + 16 + nlane; if (r1 >= N) r1 = N - 1;

    short8 a[2][4];
#pragma unroll
    for (int ks = 0; ks < 4; ks++) {
        a[0][ks] = *reinterpret_cast<const short8*>(h1 + (size_t)r0 * D + ks * 32 + quad * 8);
        a[1][ks] = *reinterpret_cast<const short8*>(h1 + (size_t)r1 * D + ks * 32 + quad * 8);
    }

    floatx4 acc[2][2];
#pragma unroll
    for (int mt = 0; mt < 2; mt++)
#pragma unroll
        for (int nt = 0; nt < 2; nt++) acc[mt][nt] = (floatx4){0.f, 0.f, 0.f, 0.f};

#pragma unroll
    for (int ks = 0; ks < 4; ks++) {
        int k0 = ks * 32;
#pragma unroll
        for (int nt = 0; nt < 2; nt++) {
            short8 bh = *reinterpret_cast<const short8*>(&sW[0][nt * 16 + nlane][k0 + quad * 8]);
            short8 bl = *reinterpret_cast<const short8*>(&sW[1][nt * 16 + nlane][k0 + quad * 8]);
            acc[0][nt] = __builtin_amdgcn_mfma_f32_16x16x32_bf16(a[0][ks], bh, acc[0][nt], 0, 0, 0);
            acc[0][nt] = __builtin_amdgcn_mfma_f32_16x16x32_bf16(a[0][ks], bl, acc[0][nt], 0, 0, 0);
            acc[1][nt] = __builtin_amdgcn_mfma_f32_16x16x32_bf16(a[1][ks], bh, acc[1][nt], 0, 0, 0);
            acc[1][nt] = __builtin_amdgcn_mfma_f32_16x16x32_bf16(a[1][ks], bl, acc[1][nt], 0, 0, 0);
        }
    }

#pragma unroll
    for (int nt = 0; nt < 2; nt++) {
        int c = c0 + nt * 16 + nlane;
#pragma unroll
        for (int mt = 0; mt < 2; mt++) {
#pragma unroll
            for (int r = 0; r < 4; r++) {
                int node = m0 + mt * 16 + quad * 4 + r;
                if (node < N) {
                    float v = acc[mt][nt][r];
                    if (c < 64) ytop2[(size_t)node * 64 + c] = v + b2[c];
                    else        z2[(size_t)node * 64 + (c - 64)] = rne_bf16(v);
                }
            }
        }
    }
}

// ---------- layer-2 gather: out[n] = ytop2[n] + (sum w*z2[col])/deg ----------
__global__ void gather_out(const unsigned short* __restrict__ z2, const int* __restrict__ rowptr4,
                           const long long* __restrict__ epL, const float* __restrict__ ytop2,
                           float* __restrict__ out, int N) {
    long long t = (long long)blockIdx.x * blockDim.x + threadIdx.x;
    int wid = (int)(t >> 6);
    int lane = threadIdx.x & 63;
    int slot = lane >> 3;
    int fl = lane & 7;
    int n = wid * 8 + slot;
    if (n >= N) return;
    int beg = rowptr4[n * 4], end = rowptr4[n * 4 + 4];
    float acc[8];
#pragma unroll
    for (int j = 0; j < 8; j++) acc[j] = 0.f;
    float ds = 0.f;
    int e = beg;
    for (; e + 7 < end; e += 8) {
        long long p[8];
#pragma unroll
        for (int u = 0; u < 8; u++) p[u] = __builtin_nontemporal_load(epL + e + u);
#pragma unroll
        for (int u = 0; u < 8; u++) {
            int c; float w; unpack_ep(p[u], c, w);
            uint4 a = *reinterpret_cast<const uint4*>(z2 + (size_t)c * 64 + fl * 8);
            accum8(acc, a, w);
            ds += w;
        }
    }
    for (; e < end; ++e) {
        long long p = __builtin_nontemporal_load(epL + e);
        int c; float w; unpack_ep(p, c, w);
        uint4 a = *reinterpret_cast<const uint4*>(z2 + (size_t)c * 64 + fl * 8);
        accum8(acc, a, w);
        ds += w;
    }
    float inv = 1.0f / (ds > 1.f ? ds : 1.f);
    const float* yt = ytop2 + (size_t)n * 64 + fl * 8;
    float* op = out + (size_t)n * 64 + fl * 8;
    float4 t0 = *reinterpret_cast<const float4*>(yt);
    float4 t1 = *reinterpret_cast<const float4*>(yt + 4);
    float4 o0 = make_float4(t0.x + acc[0] * inv, t0.y + acc[1] * inv,
                            t0.z + acc[2] * inv, t0.w + acc[3] * inv);
    float4 o1 = make_float4(t1.x + acc[4] * inv, t1.y + acc[5] * inv,
                            t1.z + acc[6] * inv, t1.w + acc[7] * inv);
    *reinterpret_cast<float4*>(op) = o0;
    *reinterpret_cast<float4*>(op + 4) = o1;
}

extern "C" void kernel_launch(void* const* d_in, const int* in_sizes, int n_in,
                              void* d_out, int out_size, void* d_ws, size_t ws_size,
                              hipStream_t stream) {
    const float* x  = (const float*)d_in[0];
    const int*   ei = (const int*)d_in[1];
    const float* ew = (const float*)d_in[2];
    const float* W0 = (const float*)d_in[3];
    const float* b0 = (const float*)d_in[4];
    const float* W1 = (const float*)d_in[5];
    const float* b1 = (const float*)d_in[6];
    const float* W2 = (const float*)d_in[7];
    const float* b2 = (const float*)d_in[8];
    float* out = (float*)d_out;

    const int N = 50000;
    const int E = in_sizes[2];          // 800000
    const int NB = N * NQ;              // 200000 bins
    const int* row = ei;
    const int* col = ei + E;

    char* base = (char*)d_ws;
    size_t ND = (size_t)N * D;
    unsigned short* x_hi   = (unsigned short*)base;               base += ND * 2;
    unsigned short* h0_hi  = (unsigned short*)base;               base += ND * 2;
    unsigned short* h1_hi  = (unsigned short*)base;               base += ND * 2;
    unsigned short* agg_hi = (unsigned short*)base;               base += ND * 2;
    int2* ep               = (int2*)base;                         base += (size_t)E * 8;
    int* rowptr4           = (int*)base;                          base += (size_t)(NB + 1) * 4;
    unsigned short* W0hi   = (unsigned short*)base;               base += 128 * 256 * 2;
    unsigned short* W0lo   = (unsigned short*)base;               base += 128 * 256 * 2;
    unsigned short* W1hi   = (unsigned short*)base;               base += 128 * 256 * 2;
    unsigned short* W1lo   = (unsigned short*)base;               base += 128 * 256 * 2;
    unsigned short* W2Chi  = (unsigned short*)base;               base += 128 * 128 * 2;
    unsigned short* W2Clo  = (unsigned short*)base;               base += 128 * 128 * 2;

    int* cnt    = (int*)h0_hi;          // CSR scratch aliases h0_hi
    int* cursor = cnt + NB;
    int* bsum   = cursor + NB;
    int* boff   = bsum + 1024;

    float* ytop2          = (float*)agg_hi;     // layer-2 scratch aliases
    unsigned short* z2    = (unsigned short*)h0_hi;
    const long long* epL  = (const long long*)ep;

    int nbScan = (NB + 255) / 256;      // 782

    // ---- prep (cast x, cast W hi/lo, hist4) ----
    hipMemsetAsync(cnt, 0, (size_t)NB * sizeof(int), stream);
    int n4 = (int)(ND / 4);
    prep_kernel<<<9695, 256, 0, stream>>>(x, x_hi, W0, W1, W2,
        W0hi, W0lo, W1hi, W1lo, W2Chi, W2Clo, row, col, cnt, n4, E);

    // ---- scans + scatter ----
    scan1_kernel<<<nbScan, 256, 0, stream>>>(cnt, rowptr4, bsum, NB);
    scan2_kernel<<<1, 1024, 0, stream>>>(bsum, boff, nbScan);
    scan3_kernel<<<(NB + 256) / 256 + 1, 256, 0, stream>>>(rowptr4, boff, cursor, NB, E);
    scatter_ranged<<<2048, 256, 0, stream>>>(row, col, ew, cursor, ep, E);

    int nWaves = (N + 3) / 4;                       // 12500 (4 nodes/wave)
    int aggBlocks = (int)(((long long)nWaves * 64 + 255) / 256);
    int nodeTiles = (N + 127) / 128;                // 391
    dim3 g128(nodeTiles, 4);

    // layer 0: x -> h0
    gather_agg_bf<<<aggBlocks, 256, 0, stream>>>(x_hi, rowptr4, epL, agg_hi, N);
    sage_gemm<true, true, D><<<g128, 256, 0, stream>>>(
        x_hi, agg_hi, W0hi, W0lo, b0, nullptr, h0_hi, N);

    // layer 1: h0 -> h1
    gather_agg_bf<<<aggBlocks, 256, 0, stream>>>(h0_hi, rowptr4, epL, agg_hi, N);
    sage_gemm<true, true, D><<<g128, 256, 0, stream>>>(
        h0_hi, agg_hi, W1hi, W1lo, b1, nullptr, h1_hi, N);

    // layer 2 (z-trick): h1 -> (ytop2, z2) -> out
    sage_gemm2<<<g128, 256, 0, stream>>>(h1_hi, W2Chi, W2Clo, b2, ytop2, z2, N);
    int nWaves2 = (N + 7) / 8;                      // 6250 (8 nodes/wave)
    int outBlocks = (int)(((long long)nWaves2 * 64 + 255) / 256);
    gather_out<<<outBlocks, 256, 0, stream>>>(z2, rowptr4, epL, ytop2, out, N);
}